// Round 6
// baseline (143.037 us; speedup 1.0000x reference)
//
#include <hip/hip_runtime.h>

// QuantLinear: out[8,11008] = x[8,4096] @ W[11008,4096]^T
// packed[i] (int32) holds ONE byte: low nibble = weight 2i, high = weight 2i+1; (q-8)*scale[idx/32].
//
// R6: amortize x-staging, lengthen tiles to cover prefetch latency.
//   Grid: 688 row-groups x split-K=4 = 2752 WGs x 256 thr (10.75 WG/CU queued, 5 resident @32KB LDS).
//   WG: 16 rows, one 1024-k quarter; stage x[8][1024] = 32 KB LDS once (1 barrier).
//   Wave: 4 rows, 4 tiles of 256 k; lane owns 4 consecutive k:
//     weights: 4x dwordx2 per tile (one per row), coalesced; distance-2 register ring
//     (x comes from LDS = lgkmcnt, so vmcnt waits never drain the weight prefetch).
//   ~400 VALU-cyc per tile -> distance-2 = ~800 cyc of independent work ~ 1 HBM latency.
//   Epilogue: 5-step shfl_xor tree + xor32; lanes 0-31 atomicAdd (out memset to 0).

#define OUT_F 11008
#define IN_F  4096

__device__ __forceinline__ void dequant4(const int2 p, const float s, float w[4]) {
    const float ns = -8.f * s;
    w[0] = fmaf((float)(p.x & 15),        s, ns);
    w[1] = fmaf((float)((p.x >> 4) & 15), s, ns);
    w[2] = fmaf((float)(p.y & 15),        s, ns);
    w[3] = fmaf((float)((p.y >> 4) & 15), s, ns);
}

__global__ __launch_bounds__(256) void qlin_kernel(
    const float* __restrict__ x,
    const int*   __restrict__ packed,
    const float* __restrict__ scales,
    float*       __restrict__ out)
{
    const int tid  = threadIdx.x;
    const int lane = tid & 63;
    const int wave = tid >> 6;
    const int b    = blockIdx.x;
    const int q    = b & 3;                  // k-quarter
    const int g    = b >> 2;                 // row-group 0..687
    const int r0   = g * 16 + wave * 4;      // wave's 4 rows
    const int kq   = q * 1024;               // global k base of quarter

    // weight/scale bases for the 4 rows (tile t adds t*128 dwords / t*8 scales)
    const int pb = r0 * 2048 + (kq >> 1) + lane * 2;
    const int sb = r0 * 128 + (kq >> 5) + (lane >> 3);

    // ---- issue weight prefetch for tiles 0,1 FIRST ----
    int2  wq[3][4];
    float sc[3][4];
#pragma unroll
    for (int r = 0; r < 4; ++r) {
        wq[0][r] = *(const int2*)(packed + pb + r * 2048);
        sc[0][r] = scales[sb + r * 128];
        wq[1][r] = *(const int2*)(packed + pb + r * 2048 + 128);
        sc[1][r] = scales[sb + r * 128 + 8];
    }

    // ---- stage x[8][1024] quarter into LDS (32 KB), fully coalesced ----
    __shared__ float xs[8 * 1024];
    {
        const float* xg = x + kq;
#pragma unroll
        for (int i = 0; i < 8; ++i) {
            const int f  = tid + i * 256;         // float4 id 0..2047
            const int m  = f >> 8;
            const int kv = (f & 255) << 2;        // float offset within quarter
            *(float4*)(xs + m * 1024 + kv) = *(const float4*)(xg + m * IN_F + kv);
        }
    }
    __syncthreads();

    float acc[32];                                // acc[r*8 + m]
#pragma unroll
    for (int i = 0; i < 32; ++i) acc[i] = 0.f;

#pragma unroll
    for (int t = 0; t < 4; ++t) {
        // distance-2 ring: issue tile t+2 before consuming tile t
        if (t < 2) {
            const int u = (t + 2) % 3;
#pragma unroll
            for (int r = 0; r < 4; ++r) {
                wq[u][r] = *(const int2*)(packed + pb + r * 2048 + (t + 2) * 128);
                sc[u][r] = scales[sb + r * 128 + (t + 2) * 8];
            }
        }

        const int c  = t % 3;
        const int kl = t * 256 + lane * 4;        // local k in quarter (lane's 4 k)

        float w[4][4];
#pragma unroll
        for (int r = 0; r < 4; ++r) dequant4(wq[c][r], sc[c][r], w[r]);

#pragma unroll
        for (int m = 0; m < 8; ++m) {
            const float4 xa = *(const float4*)(xs + m * 1024 + kl);  // ds_read_b128
#pragma unroll
            for (int r = 0; r < 4; ++r) {
                float a = acc[r * 8 + m];
                a = fmaf(w[r][0], xa.x, a);
                a = fmaf(w[r][1], xa.y, a);
                a = fmaf(w[r][2], xa.z, a);
                a = fmaf(w[r][3], xa.w, a);
                acc[r * 8 + m] = a;
            }
        }
    }

    // ---- merge tree over 32 values: lane l ends with wave-total for index l&31 ----
#pragma unroll
    for (int s = 0; s < 5; ++s) {
        const int bit = (lane >> s) & 1;
        const int n = 16 >> s;
#pragma unroll
        for (int j = 0; j < n; ++j) {
            const float u = bit ? acc[2 * j + 1] : acc[2 * j];
            const float v = bit ? acc[2 * j]     : acc[2 * j + 1];
            acc[j] = u + __shfl_xor(v, 1 << s, 64);
        }
    }
    acc[0] += __shfl_xor(acc[0], 32, 64);

    if (lane < 32) {
        const int r = lane >> 3;                  // index l = r*8 + m
        const int m = lane & 7;
        atomicAdd(out + m * OUT_F + r0 + r, acc[0]);
    }
}

extern "C" void kernel_launch(void* const* d_in, const int* in_sizes, int n_in,
                              void* d_out, int out_size, void* d_ws, size_t ws_size,
                              hipStream_t stream) {
    const float* x      = (const float*)d_in[0];
    const int*   packed = (const int*)  d_in[1];
    const float* scales = (const float*)d_in[2];
    float*       out    = (float*)d_out;

    // split-K atomics accumulate into out -> zero it first (async, graph-capturable)
    hipMemsetAsync(out, 0, (size_t)out_size * sizeof(float), stream);

    dim3 grid((OUT_F / 16) * 4), block(256);      // 2752 WGs x 4 waves
    hipLaunchKernelGGL(qlin_kernel, grid, block, 0, stream,
                       x, packed, scales, out);
}

// Round 8
// 139.269 us; speedup vs baseline: 1.0271x; 1.0271x over previous
//
#include <hip/hip_runtime.h>

// QuantLinear: out[8,11008] = x[8,4096] @ W[11008,4096]^T
// packed[i] (INT32, one per byte!) holds 2 nibbles: low = weight 2i, high = weight 2i+1;
// weight = (q-8)*scale[idx/32]. 2048 int32 per row of 4096 k.
//
// R8: R7's in-order-vmcnt pipeline with R6's CORRECT int32-unit addressing.
//   Issue order per wave:
//     1) 8x x float4 loads (OLDEST in vmcnt queue)
//     2) ALL 16 int2 weight loads + 16 scale loads for the wave's whole 1024-k strip
//     3) ds_write x -> waits only the oldest 8; weight loads stay in flight
//     4) __syncthreads (no vmem drain needed for register-dest loads)
//     5) 4 tiles consume weights in issue order -> sliding vmcnt, never a full drain
//   Grid: 688 row-groups x split-K=4 = 2752 WGs x 256 thr. WG: 16 rows, one 1024-k quarter,
//   x[8][1024] = 32 KB LDS. Wave: 4 rows; tile = 256 k; lane owns 4 consecutive k:
//     weights: dwordx2 per row per tile (512 B/wave-instr, coalesced)
//     x: ds_read_b128 at lane*16 B (conflict-free)
//   Epilogue: 5-step shfl_xor tree + xor32; lanes 0-31 atomicAdd (out memset to 0).

#define OUT_F 11008
#define IN_F  4096

__global__ __launch_bounds__(256) void qlin_kernel(
    const float* __restrict__ x,
    const int*   __restrict__ packed,
    const float* __restrict__ scales,
    float*       __restrict__ out)
{
    const int tid  = threadIdx.x;
    const int lane = tid & 63;
    const int wave = tid >> 6;
    const int b    = blockIdx.x;
    const int q    = b & 3;                  // k-quarter
    const int g    = b >> 2;                 // row-group 0..687
    const int r0   = g * 16 + wave * 4;      // wave's 4 rows
    const int kq   = q * 1024;               // global k base of quarter

    __shared__ float xs[8 * 1024];

    // ---- 1) x loads FIRST: oldest entries in the vmcnt queue ----
    float4 xv[8];
    {
        const float* xg = x + kq;
#pragma unroll
        for (int i = 0; i < 8; ++i) {
            const int f  = tid + i * 256;         // float4 id 0..2047
            const int m  = f >> 8;
            const int kv = (f & 255) << 2;
            xv[i] = *(const float4*)(xg + m * IN_F + kv);
        }
    }

    // ---- 2) ALL weight + scale loads for the strip (int32 units: lane*2 dwords = 4 k) ----
    const int pb = r0 * 2048 + (kq >> 1) + lane * 2;   // int32 offset; tile t adds t*128
    const int sb = r0 * 128 + (kq >> 5) + (lane >> 3); // scale offset; tile t adds t*8
    int2  wq[4][4];                               // [tile][row]
    float sc[4][4];
#pragma unroll
    for (int t = 0; t < 4; ++t) {
#pragma unroll
        for (int r = 0; r < 4; ++r) {
            wq[t][r] = *(const int2*)(packed + pb + r * 2048 + t * 128);
            sc[t][r] = scales[sb + r * 128 + t * 8];
        }
    }

    // ---- 3) stage x: waits only the 8 oldest loads; weights stay outstanding ----
#pragma unroll
    for (int i = 0; i < 8; ++i) {
        const int f  = tid + i * 256;
        const int m  = f >> 8;
        const int kv = (f & 255) << 2;
        *(float4*)(xs + m * 1024 + kv) = xv[i];
    }
    __syncthreads();

    float acc[32];                                // acc[r*8 + m]
#pragma unroll
    for (int i = 0; i < 32; ++i) acc[i] = 0.f;

#pragma unroll
    for (int t = 0; t < 4; ++t) {                 // consume weights in issue order
        float w[4][4];
#pragma unroll
        for (int r = 0; r < 4; ++r) {
            const int   px = wq[t][r].x, py = wq[t][r].y;
            const float s  = sc[t][r];
            const float ns = -8.f * s;
            w[r][0] = fmaf((float)(px & 15),        s, ns);   // k+0
            w[r][1] = fmaf((float)((px >> 4) & 15), s, ns);   // k+1
            w[r][2] = fmaf((float)(py & 15),        s, ns);   // k+2
            w[r][3] = fmaf((float)((py >> 4) & 15), s, ns);   // k+3
        }

        const int kl = t * 256 + lane * 4;        // local k in quarter (lane's 4 k)
#pragma unroll
        for (int m = 0; m < 8; ++m) {
            const float4 xa = *(const float4*)(xs + m * 1024 + kl);  // ds_read_b128
#pragma unroll
            for (int r = 0; r < 4; ++r) {
                float a = acc[r * 8 + m];
                a = fmaf(w[r][0], xa.x, a);
                a = fmaf(w[r][1], xa.y, a);
                a = fmaf(w[r][2], xa.z, a);
                a = fmaf(w[r][3], xa.w, a);
                acc[r * 8 + m] = a;
            }
        }
    }

    // ---- merge tree over 32 values: lane l ends with wave-total for index l&31 ----
#pragma unroll
    for (int s = 0; s < 5; ++s) {
        const int bit = (lane >> s) & 1;
        const int n = 16 >> s;
#pragma unroll
        for (int j = 0; j < n; ++j) {
            const float u = bit ? acc[2 * j + 1] : acc[2 * j];
            const float v = bit ? acc[2 * j]     : acc[2 * j + 1];
            acc[j] = u + __shfl_xor(v, 1 << s, 64);
        }
    }
    acc[0] += __shfl_xor(acc[0], 32, 64);

    if (lane < 32) {
        const int r = lane >> 3;                  // index l = r*8 + m
        const int m = lane & 7;
        atomicAdd(out + m * OUT_F + r0 + r, acc[0]);
    }
}

extern "C" void kernel_launch(void* const* d_in, const int* in_sizes, int n_in,
                              void* d_out, int out_size, void* d_ws, size_t ws_size,
                              hipStream_t stream) {
    const float* x      = (const float*)d_in[0];
    const int*   packed = (const int*)  d_in[1];
    const float* scales = (const float*)d_in[2];
    float*       out    = (float*)d_out;

    // split-K atomics accumulate into out -> zero it first (async, graph-capturable)
    hipMemsetAsync(out, 0, (size_t)out_size * sizeof(float), stream);

    dim3 grid((OUT_F / 16) * 4), block(256);      // 2752 WGs x 4 waves
    hipLaunchKernelGGL(qlin_kernel, grid, block, 0, stream,
                       x, packed, scales, out);
}